// Round 3
// baseline (53.406 us; speedup 1.0000x reference)
//
#include <hip/hip_runtime.h>
#include <stdint.h>

// Problem shape (fixed by setup_inputs):
//   x:            [B=8, N=8192, D=512] fp32
//   block_onehot: [B, N, G=16] fp32 (one-hot per token)
//   capacity = N/G = 512
//   out:          [B, G, capacity, D] fp32
// Balanced assignment -> every output row written exactly once.

#define Bn 8
#define Nn 8192
#define Dn 512
#define Gn 16
#define CAPn 512
#define CHUNK 256
#define NCHUNK (Nn / CHUNK)   // 32

typedef float f32x4 __attribute__((ext_vector_type(4)));

// Workspace layout (bytes):
//   rec16 : uint16[B*N]   (g | rank<<4)   @ 0        (131072)
//   w32   : float [B*N]                   @ 131072   (262144)
//   hist_t: int   [B][G][NCHUNK]          @ 393216   (16384)
// total 409600 B

__global__ __launch_bounds__(256) void pass_a(
    const float* __restrict__ oh, uint16_t* __restrict__ rec16,
    float* __restrict__ w32, int* __restrict__ hist_t) {
  const int blk = blockIdx.x;            // 0 .. B*NCHUNK-1
  const int b = blk / NCHUNK;
  const int c = blk % NCHUNK;
  const int tid = threadIdx.x;           // 0..255
  const int n = c * CHUNK + tid;
  const long tok = (long)b * Nn + n;

  // find first positive entry (argmax of boolean mask -> first true)
  const f32x4* p = (const f32x4*)(oh + tok * Gn);
  int g = -1;
  float w = 0.f;
#pragma unroll
  for (int j = 0; j < 4; ++j) {
    f32x4 v = p[j];
#pragma unroll
    for (int k = 0; k < 4; ++k) {
      if (g < 0 && v[k] > 0.f) { g = j * 4 + k; w = v[k]; }
    }
  }
  if (g < 0) g = 0;   // balanced inputs guarantee one-hot; w stays 0

  const int lane = tid & 63;
  const int wid = tid >> 6;              // 4 waves per block
  __shared__ int wcnt[4][Gn];

  unsigned long long mymask = 0ULL;
#pragma unroll
  for (int v = 0; v < Gn; ++v) {
    unsigned long long m = __ballot(g == v);   // 64-bit wave ballot
    if (g == v) mymask = m;
    if (lane == v) wcnt[wid][v] = __popcll(m);
  }
  __syncthreads();

  int rank = __popcll(mymask & ((1ULL << lane) - 1ULL));
#pragma unroll
  for (int ww = 0; ww < 4; ++ww)
    if (ww < wid) rank += wcnt[ww][g];

  rec16[tok] = (uint16_t)(g | (rank << 4));
  w32[tok] = w;

  if (tid < Gn) {
    int t = wcnt[0][tid] + wcnt[1][tid] + wcnt[2][tid] + wcnt[3][tid];
    hist_t[((b << 4) + tid) * NCHUNK + c] = t;   // transposed: [b][g][chunk]
  }
}

__global__ __launch_bounds__(256) void pass_c(
    const float* __restrict__ x, const uint16_t* __restrict__ rec16,
    const float* __restrict__ w32, const int* __restrict__ hist_t,
    float* __restrict__ out) {
  const int tid = threadIdx.x;
  const int lane = tid & 63;
  const int wid = tid >> 6;                       // 4 waves; 2 tokens each
  const int base = (blockIdx.x << 3) + (wid << 1);   // even token index

  const int b = base >> 13;                       // N = 8192
  const int n = base & (Nn - 1);
  const int c = n >> 8;                           // chunk (same for both tokens)

  const uint32_t recs = *(const uint32_t*)(rec16 + base);   // both tokens
  const int g0 = recs & 15,          r0 = (recs >> 4) & 511;
  const int g1 = (recs >> 16) & 15,  r1 = (recs >> 20) & 511;
  const float2 ww = *(const float2*)(w32 + base);

  // half-wave exclusive prefix over chunks < c:
  // lanes 0..31 reduce token0's (b,g0) hist row, lanes 32..63 token1's.
  const int hl = lane >> 5, l5 = lane & 31;
  const int gg = hl ? g1 : g0;
  int v = (l5 < c) ? hist_t[(((b << 4) + gg) << 5) + l5] : 0;
#pragma unroll
  for (int m = 1; m < 32; m <<= 1) v += __shfl_xor(v, m);   // stays in halves
  const int p0 = __shfl(v, 0);
  const int p1 = __shfl(v, 32);

  const long orow0 = ((long)((b << 4) + g0) << 9) + p0 + r0;
  const long orow1 = ((long)((b << 4) + g1) << 9) + p1 + r1;

  const f32x4* xs = (const f32x4*)(x + (long)base * Dn);   // 256 float4s (2 rows)
  f32x4* o0 = (f32x4*)(out + orow0 * (long)Dn);
  f32x4* o1 = (f32x4*)(out + orow1 * (long)Dn);

  f32x4 a0 = __builtin_nontemporal_load(xs + lane);
  f32x4 a1 = __builtin_nontemporal_load(xs + lane + 64);
  f32x4 a2 = __builtin_nontemporal_load(xs + lane + 128);
  f32x4 a3 = __builtin_nontemporal_load(xs + lane + 192);
  __builtin_nontemporal_store(a0 * ww.x, o0 + lane);
  __builtin_nontemporal_store(a1 * ww.x, o0 + lane + 64);
  __builtin_nontemporal_store(a2 * ww.y, o1 + lane);
  __builtin_nontemporal_store(a3 * ww.y, o1 + lane + 64);
}

extern "C" void kernel_launch(void* const* d_in, const int* in_sizes, int n_in,
                              void* d_out, int out_size, void* d_ws, size_t ws_size,
                              hipStream_t stream) {
  const float* x = (const float*)d_in[0];
  const float* oh = (const float*)d_in[1];
  float* out = (float*)d_out;

  char* ws = (char*)d_ws;
  uint16_t* rec16 = (uint16_t*)(ws + 0);
  float* w32 = (float*)(ws + 131072);
  int* hist_t = (int*)(ws + 393216);

  pass_a<<<Bn * NCHUNK, 256, 0, stream>>>(oh, rec16, w32, hist_t);
  pass_c<<<(Bn * Nn) / 8, 256, 0, stream>>>(x, rec16, w32, hist_t, out);
}

// Round 4
// 49.945 us; speedup vs baseline: 1.0693x; 1.0693x over previous
//
#include <hip/hip_runtime.h>
#include <stdint.h>

// Problem shape (fixed by setup_inputs):
//   x:            [B=8, N=8192, D=512] fp32
//   block_onehot: [B, N, G=16] fp32 (one-hot per token)
//   capacity = N/G = 512
//   out:          [B, G, capacity, D] fp32
// Balanced assignment -> every output row written exactly once.

#define Bn 8
#define Nn 8192
#define Dn 512
#define Gn 16
#define CAPn 512
#define CHUNK 256
#define NCHUNK (Nn / CHUNK)   // 32

typedef float f32x4 __attribute__((ext_vector_type(4)));

// Workspace layout (bytes):
//   rec16 : uint16[B*N]   (g | rank<<4)   @ 0        (131072)
//   w32   : float [B*N]                   @ 131072   (262144)
//   hist_t: int   [B][G][NCHUNK]          @ 393216   (16384)
// total 409600 B

__global__ __launch_bounds__(256) void pass_a(
    const float* __restrict__ oh, uint16_t* __restrict__ rec16,
    float* __restrict__ w32, int* __restrict__ hist_t) {
  const int blk = blockIdx.x;            // 0 .. B*NCHUNK-1
  const int b = blk / NCHUNK;
  const int c = blk % NCHUNK;
  const int tid = threadIdx.x;           // 0..255
  const int n = c * CHUNK + tid;
  const long tok = (long)b * Nn + n;

  // find first positive entry (argmax of boolean mask -> first true)
  const f32x4* p = (const f32x4*)(oh + tok * Gn);
  int g = -1;
  float w = 0.f;
#pragma unroll
  for (int j = 0; j < 4; ++j) {
    f32x4 v = p[j];
#pragma unroll
    for (int k = 0; k < 4; ++k) {
      if (g < 0 && v[k] > 0.f) { g = j * 4 + k; w = v[k]; }
    }
  }
  if (g < 0) g = 0;   // balanced inputs guarantee one-hot; w stays 0

  const int lane = tid & 63;
  const int wid = tid >> 6;              // 4 waves per block
  __shared__ int wcnt[4][Gn];

  unsigned long long mymask = 0ULL;
#pragma unroll
  for (int v = 0; v < Gn; ++v) {
    unsigned long long m = __ballot(g == v);   // 64-bit wave ballot
    if (g == v) mymask = m;
    if (lane == v) wcnt[wid][v] = __popcll(m);
  }
  __syncthreads();

  int rank = __popcll(mymask & ((1ULL << lane) - 1ULL));
#pragma unroll
  for (int ww = 0; ww < 4; ++ww)
    if (ww < wid) rank += wcnt[ww][g];

  rec16[tok] = (uint16_t)(g | (rank << 4));
  w32[tok] = w;

  if (tid < Gn) {
    int t = wcnt[0][tid] + wcnt[1][tid] + wcnt[2][tid] + wcnt[3][tid];
    hist_t[((b << 4) + tid) * NCHUNK + c] = t;   // transposed: [b][g][chunk]
  }
}

__global__ __launch_bounds__(256) void pass_c(
    const float* __restrict__ x, const uint16_t* __restrict__ rec16,
    const float* __restrict__ w32, const int* __restrict__ hist_t,
    float* __restrict__ out) {
  const int tid = threadIdx.x;
  const int lane = tid & 63;
  const int wid = tid >> 6;                       // 4 waves; 2 tokens each
  const int base = (blockIdx.x << 3) + (wid << 1);   // even token index

  const int b = base >> 13;                       // N = 8192
  const int n = base & (Nn - 1);
  const int c = n >> 8;                           // chunk (same for both tokens)

  const uint32_t recs = *(const uint32_t*)(rec16 + base);   // both tokens
  const int g0 = recs & 15,          r0 = (recs >> 4) & 511;
  const int g1 = (recs >> 16) & 15,  r1 = (recs >> 20) & 511;
  const float2 ww = *(const float2*)(w32 + base);

  // half-wave exclusive prefix over chunks < c:
  // lanes 0..31 reduce token0's (b,g0) hist row, lanes 32..63 token1's.
  const int hl = lane >> 5, l5 = lane & 31;
  const int gg = hl ? g1 : g0;
  int v = (l5 < c) ? hist_t[(((b << 4) + gg) << 5) + l5] : 0;
#pragma unroll
  for (int m = 1; m < 32; m <<= 1) v += __shfl_xor(v, m);   // stays in halves
  const int p0 = __shfl(v, 0);
  const int p1 = __shfl(v, 32);

  const long orow0 = ((long)((b << 4) + g0) << 9) + p0 + r0;
  const long orow1 = ((long)((b << 4) + g1) << 9) + p1 + r1;

  const f32x4* xs = (const f32x4*)(x + (long)base * Dn);   // 256 float4s (2 rows)
  f32x4* o0 = (f32x4*)(out + orow0 * (long)Dn);
  f32x4* o1 = (f32x4*)(out + orow1 * (long)Dn);

  // plain cached loads/stores — nt hints regressed (R3): nt bypasses L2
  // write-combining on gfx950.
  f32x4 a0 = xs[lane];
  f32x4 a1 = xs[lane + 64];
  f32x4 a2 = xs[lane + 128];
  f32x4 a3 = xs[lane + 192];
  o0[lane]      = a0 * ww.x;
  o0[lane + 64] = a1 * ww.x;
  o1[lane]      = a2 * ww.y;
  o1[lane + 64] = a3 * ww.y;
}

extern "C" void kernel_launch(void* const* d_in, const int* in_sizes, int n_in,
                              void* d_out, int out_size, void* d_ws, size_t ws_size,
                              hipStream_t stream) {
  const float* x = (const float*)d_in[0];
  const float* oh = (const float*)d_in[1];
  float* out = (float*)d_out;

  char* ws = (char*)d_ws;
  uint16_t* rec16 = (uint16_t*)(ws + 0);
  float* w32 = (float*)(ws + 131072);
  int* hist_t = (int*)(ws + 393216);

  pass_a<<<Bn * NCHUNK, 256, 0, stream>>>(oh, rec16, w32, hist_t);
  pass_c<<<(Bn * Nn) / 8, 256, 0, stream>>>(x, rec16, w32, hist_t, out);
}